// Round 1
// baseline (668.186 us; speedup 1.0000x reference)
//
#include <hip/hip_runtime.h>

#define B_  4
#define C_  256     // C_IN == LATENT == 256
#define N_  4096    // H*W
#define SCALE 0.0625f   // 1/sqrt(256)

typedef short s8v __attribute__((ext_vector_type(8)));
typedef float f4v __attribute__((ext_vector_type(4)));

// round-to-nearest-even fp32 -> bf16 (values are finite; no NaN handling needed)
static __device__ __forceinline__ ushort f2bf(float f) {
  union { float f; uint u; } v; v.f = f;
  return (ushort)((v.u + 0x7FFFu + ((v.u >> 16) & 1u)) >> 16);
}

// ---------------------------------------------------------------------------
// QKV projection, fp32 compute, bf16 outputs.
//   p = blockIdx.z>>2 selects {q,k,v}; b = blockIdx.z&3.
//   q,k written TRANSPOSED as [b][n][latent] (so flash MFMA A/B frags are
//   contiguous 16B loads); v written natural [b][latent][n].
// grid (4, 32, 12), block 256. Each block: 8 latent rows x 1024 columns.
// ---------------------------------------------------------------------------
__global__ __launch_bounds__(256) void qkv_proj(
    const float* __restrict__ x,
    const float* __restrict__ Wq, const float* __restrict__ bq,
    const float* __restrict__ Wk, const float* __restrict__ bk,
    const float* __restrict__ Wv, const float* __restrict__ bv,
    ushort* __restrict__ q_t, ushort* __restrict__ k_t, ushort* __restrict__ v_bf)
{
  const int p = blockIdx.z >> 2;
  const int b = blockIdx.z & 3;
  const float* W  = (p == 0) ? Wq : (p == 1) ? Wk : Wv;
  const float* bi = (p == 0) ? bq : (p == 1) ? bk : bv;
  const int l0 = blockIdx.y * 8;
  const int n  = blockIdx.x * 1024 + threadIdx.x * 4;

  __shared__ float w_lds[8 * 256];
  for (int i = threadIdx.x; i < 2048; i += 256) w_lds[i] = W[l0 * 256 + i];
  __syncthreads();

  float acc[8][4];
  #pragma unroll
  for (int r = 0; r < 8; ++r) { acc[r][0]=0.f; acc[r][1]=0.f; acc[r][2]=0.f; acc[r][3]=0.f; }

  const float* xp = x + (size_t)b * ((size_t)C_ * N_) + n;
  for (int c4 = 0; c4 < 256; c4 += 4) {
    float4 x0 = *(const float4*)(xp + (size_t)(c4 + 0) * N_);
    float4 x1 = *(const float4*)(xp + (size_t)(c4 + 1) * N_);
    float4 x2 = *(const float4*)(xp + (size_t)(c4 + 2) * N_);
    float4 x3 = *(const float4*)(xp + (size_t)(c4 + 3) * N_);
    #pragma unroll
    for (int r = 0; r < 8; ++r) {
      float4 w = *(const float4*)&w_lds[r * 256 + c4];
      acc[r][0] += w.x * x0.x + w.y * x1.x + w.z * x2.x + w.w * x3.x;
      acc[r][1] += w.x * x0.y + w.y * x1.y + w.z * x2.y + w.w * x3.y;
      acc[r][2] += w.x * x0.z + w.y * x1.z + w.z * x2.z + w.w * x3.z;
      acc[r][3] += w.x * x0.w + w.y * x1.w + w.z * x2.w + w.w * x3.w;
    }
  }

  if (p < 2) {
    // transposed store: out[b][n+j][l0..l0+7] -> 8 bf16 = one 16B store per j
    ushort* outp = (p == 0) ? q_t : k_t;
    #pragma unroll
    for (int j = 0; j < 4; ++j) {
      uint u0 = (uint)f2bf(acc[0][j] + bi[l0+0]) | ((uint)f2bf(acc[1][j] + bi[l0+1]) << 16);
      uint u1 = (uint)f2bf(acc[2][j] + bi[l0+2]) | ((uint)f2bf(acc[3][j] + bi[l0+3]) << 16);
      uint u2 = (uint)f2bf(acc[4][j] + bi[l0+4]) | ((uint)f2bf(acc[5][j] + bi[l0+5]) << 16);
      uint u3 = (uint)f2bf(acc[6][j] + bi[l0+6]) | ((uint)f2bf(acc[7][j] + bi[l0+7]) << 16);
      *(uint4*)(outp + (size_t)(b * N_ + n + j) * C_ + l0) = make_uint4(u0, u1, u2, u3);
    }
  } else {
    // natural store: v[b][l0+r][n..n+3] -> 8B per row
    #pragma unroll
    for (int r = 0; r < 8; ++r) {
      float bb = bi[l0 + r];
      *(ushort4*)(v_bf + (size_t)(b * C_ + l0 + r) * N_ + n) =
          make_ushort4(f2bf(acc[r][0]+bb), f2bf(acc[r][1]+bb),
                       f2bf(acc[r][2]+bb), f2bf(acc[r][3]+bb));
    }
  }
}

// ---------------------------------------------------------------------------
// Flash attention (no-max softmax; overflow impossible: |s| <= 16).
//   res[b][c][j] = (sum_i v[c,i] * exp(q_i.k_j/16)) / (sum_i exp(q_i.k_j/16))
// Block: 4 waves, 16 output columns (tj), TI=64 per iter (16 ti rows/wave).
// QK: A = q^T rows (global 16B), B = k_lds rows. PV: A = v rows (global 16B),
// B = p_lds (P written in C/D layout as b64, read in B layout as b128).
// grid (256, 4), block 256.
// ---------------------------------------------------------------------------
__global__ __launch_bounds__(256) void flash_attn(
    const ushort* __restrict__ q_t, const ushort* __restrict__ k_t,
    const ushort* __restrict__ v_bf, float* __restrict__ res)
{
  const int j0  = blockIdx.x * 16;
  const int b   = blockIdx.y;
  const int tid = threadIdx.x;
  const int lane = tid & 63;
  const int wave = tid >> 6;
  const int l16  = lane & 15;
  const int quad = lane >> 4;

  __shared__ __align__(16) ushort k_lds[16 * 264];  // [tj][c], +8 pad (16B-aligned rows)
  __shared__ __align__(16) ushort p_lds[16 * 72];   // [tj][ti], +8 pad
  __shared__ float denom[16];

  if (tid < 16) denom[tid] = 0.f;

  { // stage k^T tile: rows j0..j0+15, 256 bf16 each; 16 bf16 per thread
    const int row = tid >> 4;
    const int col = (tid & 15) * 16;
    const uint4* src = (const uint4*)(k_t + ((size_t)(b * N_ + j0 + row) * C_ + col));
    uint4 a0 = src[0];
    uint4 a1 = src[1];
    *(uint4*)(k_lds + row * 264 + col)     = a0;
    *(uint4*)(k_lds + row * 264 + col + 8) = a1;
  }
  __syncthreads();

  f4v acc[4];
  #pragma unroll
  for (int mt = 0; mt < 4; ++mt) acc[mt] = (f4v){0.f, 0.f, 0.f, 0.f};
  float dpart = 0.f;

  const int c_base = wave * 64;                       // PV c-range of this wave
  const ushort* krow   = k_lds + l16 * 264 + quad * 8;    // B-frag source (QK)
  const ushort* prow_r = p_lds + l16 * 72 + quad * 8;     // B-frag source (PV)
  ushort*       prow_w = p_lds + l16 * 72 + wave * 16 + quad * 4;  // C/D-layout write

  for (int i0 = 0; i0 < N_; i0 += 64) {
    // ---- QK^T: wave's 16(ti) x 16(tj) s-tile, K-loop over c=256 ----
    f4v s = (f4v){0.f, 0.f, 0.f, 0.f};
    const ushort* qrow = q_t + (size_t)(b * N_ + i0 + wave * 16 + l16) * C_ + quad * 8;
    #pragma unroll
    for (int cs = 0; cs < 8; ++cs) {
      s8v a  = *(const s8v*)(qrow + cs * 32);
      s8v kb = *(const s8v*)(krow + cs * 32);
      s = __builtin_amdgcn_mfma_f32_16x16x32_bf16(a, kb, s, 0, 0, 0);
    }
    // exp (no max-subtraction needed), denom partial (lane's 4 regs share tj=l16)
    float e0 = __expf(s[0] * SCALE);
    float e1 = __expf(s[1] * SCALE);
    float e2 = __expf(s[2] * SCALE);
    float e3 = __expf(s[3] * SCALE);
    dpart += (e0 + e1) + (e2 + e3);
    // write P: rows ti_local = wave*16 + quad*4 + {0..3}, col tj = l16
    *(ushort4*)prow_w = make_ushort4(f2bf(e0), f2bf(e1), f2bf(e2), f2bf(e3));
    __syncthreads();
    // ---- P.V: out[c][tj] += v[c, i0..i0+63] * p[.., tj] ----
    #pragma unroll
    for (int ks = 0; ks < 2; ++ks) {
      s8v pb = *(const s8v*)(prow_r + ks * 32);
      const ushort* vbase = v_bf + (size_t)(b * C_ + c_base + l16) * N_ + i0 + ks * 32 + quad * 8;
      #pragma unroll
      for (int mt = 0; mt < 4; ++mt) {
        s8v av = *(const s8v*)(vbase + (size_t)mt * 16 * N_);
        acc[mt] = __builtin_amdgcn_mfma_f32_16x16x32_bf16(av, pb, acc[mt], 0, 0, 0);
      }
    }
    __syncthreads();
  }

  // denominator: combine quads (lanes l, l^16, l^32 share tj), then waves via LDS
  dpart += __shfl_xor(dpart, 16);
  dpart += __shfl_xor(dpart, 32);
  if (lane < 16) atomicAdd(&denom[lane], dpart);
  __syncthreads();

  const float dinv = 1.0f / denom[l16];
  #pragma unroll
  for (int mt = 0; mt < 4; ++mt) {
    #pragma unroll
    for (int r = 0; r < 4; ++r) {
      const int c = c_base + mt * 16 + quad * 4 + r;   // D row -> c
      res[(size_t)(b * C_ + c) * N_ + j0 + l16] = acc[mt][r] * dinv;
    }
  }
}

// ---------------------------------------------------------------------------
// Output projection: out[b][co][n] = bo[co] + sum_l Wo[co][l] * res[b][l][n]
// fp32 in/out, same structure as qkv_proj. grid (4, 32, 4), block 256.
// ---------------------------------------------------------------------------
__global__ __launch_bounds__(256) void out_proj(
    const float* __restrict__ res, const float* __restrict__ Wo,
    const float* __restrict__ bo, float* __restrict__ out)
{
  const int b  = blockIdx.z;
  const int l0 = blockIdx.y * 8;
  const int n  = blockIdx.x * 1024 + threadIdx.x * 4;

  __shared__ float w_lds[8 * 256];
  for (int i = threadIdx.x; i < 2048; i += 256) w_lds[i] = Wo[l0 * 256 + i];
  __syncthreads();

  float acc[8][4];
  #pragma unroll
  for (int r = 0; r < 8; ++r) { acc[r][0]=0.f; acc[r][1]=0.f; acc[r][2]=0.f; acc[r][3]=0.f; }

  const float* rp = res + (size_t)b * ((size_t)C_ * N_) + n;
  for (int c4 = 0; c4 < 256; c4 += 4) {
    float4 x0 = *(const float4*)(rp + (size_t)(c4 + 0) * N_);
    float4 x1 = *(const float4*)(rp + (size_t)(c4 + 1) * N_);
    float4 x2 = *(const float4*)(rp + (size_t)(c4 + 2) * N_);
    float4 x3 = *(const float4*)(rp + (size_t)(c4 + 3) * N_);
    #pragma unroll
    for (int r = 0; r < 8; ++r) {
      float4 w = *(const float4*)&w_lds[r * 256 + c4];
      acc[r][0] += w.x * x0.x + w.y * x1.x + w.z * x2.x + w.w * x3.x;
      acc[r][1] += w.x * x0.y + w.y * x1.y + w.z * x2.y + w.w * x3.y;
      acc[r][2] += w.x * x0.z + w.y * x1.z + w.z * x2.z + w.w * x3.z;
      acc[r][3] += w.x * x0.w + w.y * x1.w + w.z * x2.w + w.w * x3.w;
    }
  }

  #pragma unroll
  for (int r = 0; r < 8; ++r) {
    float bb = bo[l0 + r];
    *(float4*)(out + (size_t)(b * C_ + l0 + r) * N_ + n) =
        make_float4(acc[r][0]+bb, acc[r][1]+bb, acc[r][2]+bb, acc[r][3]+bb);
  }
}

// ---------------------------------------------------------------------------
extern "C" void kernel_launch(void* const* d_in, const int* in_sizes, int n_in,
                              void* d_out, int out_size, void* d_ws, size_t ws_size,
                              hipStream_t stream)
{
  const float* x  = (const float*)d_in[0];
  const float* Wq = (const float*)d_in[1];
  const float* bq = (const float*)d_in[2];
  const float* Wk = (const float*)d_in[3];
  const float* bk = (const float*)d_in[4];
  const float* Wv = (const float*)d_in[5];
  const float* bv = (const float*)d_in[6];
  const float* Wo = (const float*)d_in[7];
  const float* bo = (const float*)d_in[8];
  float* out = (float*)d_out;

  // workspace layout (40 MB total):
  //   q_t  [B][N][L] bf16  : 8 MB   (transposed)
  //   k_t  [B][N][L] bf16  : 8 MB   (transposed)
  //   v_bf [B][L][N] bf16  : 8 MB   (natural)
  //   res  [B][L][N] fp32  : 16 MB
  char* ws = (char*)d_ws;
  ushort* q_t  = (ushort*)(ws);
  ushort* k_t  = (ushort*)(ws + (size_t)8  * 1024 * 1024);
  ushort* v_bf = (ushort*)(ws + (size_t)16 * 1024 * 1024);
  float*  res  = (float*) (ws + (size_t)24 * 1024 * 1024);

  qkv_proj<<<dim3(4, 32, 12), dim3(256), 0, stream>>>(x, Wq, bq, Wk, bk, Wv, bv, q_t, k_t, v_bf);
  flash_attn<<<dim3(256, 4), dim3(256), 0, stream>>>(q_t, k_t, v_bf, res);
  out_proj<<<dim3(4, 32, 4), dim3(256), 0, stream>>>(res, Wo, bo, out);
}

// Round 2
// 599.972 us; speedup vs baseline: 1.1137x; 1.1137x over previous
//
#include <hip/hip_runtime.h>

#define B_  4
#define C_  256     // C_IN == LATENT == 256
#define N_  4096    // H*W
#define SCALE 0.0625f   // 1/sqrt(256)

typedef short s8v __attribute__((ext_vector_type(8)));
typedef float f4v __attribute__((ext_vector_type(4)));

// round-to-nearest-even fp32 -> bf16 (values are finite; no NaN handling needed)
static __device__ __forceinline__ ushort f2bf(float f) {
  union { float f; uint u; } v; v.f = f;
  return (ushort)((v.u + 0x7FFFu + ((v.u >> 16) & 1u)) >> 16);
}

// ---------------------------------------------------------------------------
// QKV projection, fp32 compute, bf16 outputs (unchanged from R1 — correct).
//   q,k written TRANSPOSED as [b][n][latent]; v natural [b][latent][n].
// grid (4, 32, 12), block 256.
// ---------------------------------------------------------------------------
__global__ __launch_bounds__(256) void qkv_proj(
    const float* __restrict__ x,
    const float* __restrict__ Wq, const float* __restrict__ bq,
    const float* __restrict__ Wk, const float* __restrict__ bk,
    const float* __restrict__ Wv, const float* __restrict__ bv,
    ushort* __restrict__ q_t, ushort* __restrict__ k_t, ushort* __restrict__ v_bf)
{
  const int p = blockIdx.z >> 2;
  const int b = blockIdx.z & 3;
  const float* W  = (p == 0) ? Wq : (p == 1) ? Wk : Wv;
  const float* bi = (p == 0) ? bq : (p == 1) ? bk : bv;
  const int l0 = blockIdx.y * 8;
  const int n  = blockIdx.x * 1024 + threadIdx.x * 4;

  __shared__ float w_lds[8 * 256];
  for (int i = threadIdx.x; i < 2048; i += 256) w_lds[i] = W[l0 * 256 + i];
  __syncthreads();

  float acc[8][4];
  #pragma unroll
  for (int r = 0; r < 8; ++r) { acc[r][0]=0.f; acc[r][1]=0.f; acc[r][2]=0.f; acc[r][3]=0.f; }

  const float* xp = x + (size_t)b * ((size_t)C_ * N_) + n;
  for (int c4 = 0; c4 < 256; c4 += 4) {
    float4 x0 = *(const float4*)(xp + (size_t)(c4 + 0) * N_);
    float4 x1 = *(const float4*)(xp + (size_t)(c4 + 1) * N_);
    float4 x2 = *(const float4*)(xp + (size_t)(c4 + 2) * N_);
    float4 x3 = *(const float4*)(xp + (size_t)(c4 + 3) * N_);
    #pragma unroll
    for (int r = 0; r < 8; ++r) {
      float4 w = *(const float4*)&w_lds[r * 256 + c4];
      acc[r][0] += w.x * x0.x + w.y * x1.x + w.z * x2.x + w.w * x3.x;
      acc[r][1] += w.x * x0.y + w.y * x1.y + w.z * x2.y + w.w * x3.y;
      acc[r][2] += w.x * x0.z + w.y * x1.z + w.z * x2.z + w.w * x3.z;
      acc[r][3] += w.x * x0.w + w.y * x1.w + w.z * x2.w + w.w * x3.w;
    }
  }

  if (p < 2) {
    ushort* outp = (p == 0) ? q_t : k_t;
    #pragma unroll
    for (int j = 0; j < 4; ++j) {
      uint u0 = (uint)f2bf(acc[0][j] + bi[l0+0]) | ((uint)f2bf(acc[1][j] + bi[l0+1]) << 16);
      uint u1 = (uint)f2bf(acc[2][j] + bi[l0+2]) | ((uint)f2bf(acc[3][j] + bi[l0+3]) << 16);
      uint u2 = (uint)f2bf(acc[4][j] + bi[l0+4]) | ((uint)f2bf(acc[5][j] + bi[l0+5]) << 16);
      uint u3 = (uint)f2bf(acc[6][j] + bi[l0+6]) | ((uint)f2bf(acc[7][j] + bi[l0+7]) << 16);
      *(uint4*)(outp + (size_t)(b * N_ + n + j) * C_ + l0) = make_uint4(u0, u1, u2, u3);
    }
  } else {
    #pragma unroll
    for (int r = 0; r < 8; ++r) {
      float bb = bi[l0 + r];
      *(ushort4*)(v_bf + (size_t)(b * C_ + l0 + r) * N_ + n) =
          make_ushort4(f2bf(acc[r][0]+bb), f2bf(acc[r][1]+bb),
                       f2bf(acc[r][2]+bb), f2bf(acc[r][3]+bb));
    }
  }
}

// ---------------------------------------------------------------------------
// flash2: TJ=64 per block, TI=64 per iter, i-range split 4 ways.
//   Block = 4 waves. Wave w: QK tj-tile (jb + w*16) with K-fragments held in
//   REGISTERS for the whole kernel; PV c-range w*64 for all 64 tj.
//   Partial numerators/denominators combined via global fp32 atomicAdd into
//   zero-initialized res/den. Division deferred to out_proj epilogue.
// grid (64, 4, 4) = (tj-blocks, i-segments, batch), block 256.
// ---------------------------------------------------------------------------
__global__ __launch_bounds__(256, 3) void flash2(
    const ushort* __restrict__ q_t, const ushort* __restrict__ k_t,
    const ushort* __restrict__ v_bf, float* __restrict__ res,
    float* __restrict__ den)
{
  const int jb    = blockIdx.x * 64;
  const int ibase = blockIdx.y * 1024;
  const int b     = blockIdx.z;
  const int tid   = threadIdx.x;
  const int lane  = tid & 63;
  const int wave  = tid >> 6;
  const int l16   = lane & 15;
  const int quad  = lane >> 4;

  // P tile [tj 64][ti 64], row stride 72 ushorts (144B = 9 16B-groups: 2-way
  // max on b128 reads and ushort4 writes — free per m136).
  __shared__ ushort p_lds[64][72];

  // K fragments for this wave's tj-tile, full c=256: 8 x s8v, resident all kernel
  s8v kf[8];
  {
    const ushort* kp = k_t + (size_t)(b * N_ + jb + wave * 16 + l16) * C_ + quad * 8;
    #pragma unroll
    for (int cs = 0; cs < 8; ++cs) kf[cs] = *(const s8v*)(kp + cs * 32);
  }

  f4v acc[4][4];
  #pragma unroll
  for (int m = 0; m < 4; ++m)
    #pragma unroll
    for (int t = 0; t < 4; ++t) acc[m][t] = (f4v){0.f, 0.f, 0.f, 0.f};
  float dacc = 0.f;

  const ushort* qbase = q_t + (size_t)(b * N_) * C_ + (size_t)l16 * C_ + quad * 8;
  const ushort* vp[4];
  #pragma unroll
  for (int m = 0; m < 4; ++m)
    vp[m] = v_bf + (size_t)(b * C_ + wave * 64 + m * 16 + l16) * N_ + quad * 8;

  for (int it = 0; it < 16; ++it) {
    const int i0 = ibase + it * 64;

    // ---- QK phase: 4 ti-tiles, B-frags from registers, A from global (L1-shared) ----
    #pragma unroll
    for (int tt = 0; tt < 4; ++tt) {
      f4v s = (f4v){0.f, 0.f, 0.f, 0.f};
      const ushort* qp = qbase + (size_t)(i0 + tt * 16) * C_;
      #pragma unroll
      for (int cs = 0; cs < 8; ++cs) {
        s8v a = *(const s8v*)(qp + cs * 32);
        s = __builtin_amdgcn_mfma_f32_16x16x32_bf16(a, kf[cs], s, 0, 0, 0);
      }
      float e0 = __expf(s[0] * SCALE);
      float e1 = __expf(s[1] * SCALE);
      float e2 = __expf(s[2] * SCALE);
      float e3 = __expf(s[3] * SCALE);
      dacc += (e0 + e1) + (e2 + e3);
      // C-layout write: (ti = tt*16 + quad*4 + r, tj = wave*16 + l16)
      *(ushort4*)&p_lds[wave * 16 + l16][tt * 16 + quad * 4] =
          make_ushort4(f2bf(e0), f2bf(e1), f2bf(e2), f2bf(e3));
    }
    __syncthreads();

    // ---- PV phase: c-tiles m=0..3 (c = wave*64 + m*16), all 4 tj-tiles ----
    #pragma unroll
    for (int ks = 0; ks < 2; ++ks) {
      s8v pb[4];
      #pragma unroll
      for (int t = 0; t < 4; ++t)
        pb[t] = *(const s8v*)&p_lds[t * 16 + l16][ks * 32 + quad * 8];
      #pragma unroll
      for (int m = 0; m < 4; ++m) {
        s8v av = *(const s8v*)(vp[m] + i0 + ks * 32);
        #pragma unroll
        for (int t = 0; t < 4; ++t)
          acc[m][t] = __builtin_amdgcn_mfma_f32_16x16x32_bf16(av, pb[t], acc[m][t], 0, 0, 0);
      }
    }
    __syncthreads();
  }

  // ---- denom: lanes l, l^16, l^32 share tj; butterfly then one atomic per tj ----
  dacc += __shfl_xor(dacc, 16);
  dacc += __shfl_xor(dacc, 32);
  if (lane < 16) atomicAdd(&den[b * N_ + jb + wave * 16 + l16], dacc);

  // ---- numerator partial: atomic add into res (zeroed by memset) ----
  #pragma unroll
  for (int m = 0; m < 4; ++m)
    #pragma unroll
    for (int t = 0; t < 4; ++t)
      #pragma unroll
      for (int r = 0; r < 4; ++r)
        atomicAdd(&res[(size_t)(b * C_ + wave * 64 + m * 16 + quad * 4 + r) * N_
                       + jb + t * 16 + l16],
                  acc[m][t][r]);
}

// ---------------------------------------------------------------------------
// Output projection with fused softmax normalization:
//   out[b][co][n] = bo[co] + (sum_l Wo[co][l] * res[b][l][n]) / den[b][n]
// grid (4, 32, 4), block 256.
// ---------------------------------------------------------------------------
__global__ __launch_bounds__(256) void out_proj(
    const float* __restrict__ res, const float* __restrict__ Wo,
    const float* __restrict__ bo, const float* __restrict__ den,
    float* __restrict__ out)
{
  const int b  = blockIdx.z;
  const int l0 = blockIdx.y * 8;
  const int n  = blockIdx.x * 1024 + threadIdx.x * 4;

  __shared__ float w_lds[8 * 256];
  for (int i = threadIdx.x; i < 2048; i += 256) w_lds[i] = Wo[l0 * 256 + i];
  __syncthreads();

  float acc[8][4];
  #pragma unroll
  for (int r = 0; r < 8; ++r) { acc[r][0]=0.f; acc[r][1]=0.f; acc[r][2]=0.f; acc[r][3]=0.f; }

  const float* rp = res + (size_t)b * ((size_t)C_ * N_) + n;
  for (int c4 = 0; c4 < 256; c4 += 4) {
    float4 x0 = *(const float4*)(rp + (size_t)(c4 + 0) * N_);
    float4 x1 = *(const float4*)(rp + (size_t)(c4 + 1) * N_);
    float4 x2 = *(const float4*)(rp + (size_t)(c4 + 2) * N_);
    float4 x3 = *(const float4*)(rp + (size_t)(c4 + 3) * N_);
    #pragma unroll
    for (int r = 0; r < 8; ++r) {
      float4 w = *(const float4*)&w_lds[r * 256 + c4];
      acc[r][0] += w.x * x0.x + w.y * x1.x + w.z * x2.x + w.w * x3.x;
      acc[r][1] += w.x * x0.y + w.y * x1.y + w.z * x2.y + w.w * x3.y;
      acc[r][2] += w.x * x0.z + w.y * x1.z + w.z * x2.z + w.w * x3.z;
      acc[r][3] += w.x * x0.w + w.y * x1.w + w.z * x2.w + w.w * x3.w;
    }
  }

  float4 dv = *(const float4*)(den + (size_t)b * N_ + n);
  float di0 = 1.0f / dv.x, di1 = 1.0f / dv.y, di2 = 1.0f / dv.z, di3 = 1.0f / dv.w;

  #pragma unroll
  for (int r = 0; r < 8; ++r) {
    float bb = bo[l0 + r];
    *(float4*)(out + (size_t)(b * C_ + l0 + r) * N_ + n) =
        make_float4(acc[r][0]*di0 + bb, acc[r][1]*di1 + bb,
                    acc[r][2]*di2 + bb, acc[r][3]*di3 + bb);
  }
}

// ---------------------------------------------------------------------------
extern "C" void kernel_launch(void* const* d_in, const int* in_sizes, int n_in,
                              void* d_out, int out_size, void* d_ws, size_t ws_size,
                              hipStream_t stream)
{
  const float* x  = (const float*)d_in[0];
  const float* Wq = (const float*)d_in[1];
  const float* bq = (const float*)d_in[2];
  const float* Wk = (const float*)d_in[3];
  const float* bk = (const float*)d_in[4];
  const float* Wv = (const float*)d_in[5];
  const float* bv = (const float*)d_in[6];
  const float* Wo = (const float*)d_in[7];
  const float* bo = (const float*)d_in[8];
  float* out = (float*)d_out;

  // workspace layout (40 MB + 64 KB):
  //   q_t  [B][N][L] bf16  : 8 MB   (transposed)
  //   k_t  [B][N][L] bf16  : 8 MB   (transposed)
  //   v_bf [B][L][N] bf16  : 8 MB   (natural)
  //   res  [B][L][N] fp32  : 16 MB  (unnormalized numerator, atomic target)
  //   den  [B][N]    fp32  : 64 KB  (softmax denominators, atomic target)
  char* ws = (char*)d_ws;
  ushort* q_t  = (ushort*)(ws);
  ushort* k_t  = (ushort*)(ws + (size_t)8  * 1024 * 1024);
  ushort* v_bf = (ushort*)(ws + (size_t)16 * 1024 * 1024);
  float*  res  = (float*) (ws + (size_t)24 * 1024 * 1024);
  float*  den  = (float*) (ws + (size_t)40 * 1024 * 1024);

  // zero the atomic targets (res and den are contiguous)
  hipMemsetAsync(res, 0, (size_t)16 * 1024 * 1024 + (size_t)B_ * N_ * sizeof(float), stream);

  qkv_proj<<<dim3(4, 32, 12), dim3(256), 0, stream>>>(x, Wq, bq, Wk, bk, Wv, bv, q_t, k_t, v_bf);
  flash2<<<dim3(64, 4, 4), dim3(256), 0, stream>>>(q_t, k_t, v_bf, res, den);
  out_proj<<<dim3(4, 32, 4), dim3(256), 0, stream>>>(res, Wo, bo, den, out);
}